// Round 13
// baseline (142.158 us; speedup 1.0000x reference)
//
#include <hip/hip_runtime.h>
#include <hip/hip_bf16.h>

typedef short bf16x8 __attribute__((ext_vector_type(8)));
typedef short s16x4  __attribute__((ext_vector_type(4)));
typedef short s16x8  __attribute__((ext_vector_type(8)));
typedef float f32x4  __attribute__((ext_vector_type(4)));

static __device__ __forceinline__ void async_cp16(const void* g, void* l) {
  __builtin_amdgcn_global_load_lds(
      (const __attribute__((address_space(1))) unsigned int*)g,
      (__attribute__((address_space(3))) unsigned int*)l, 16, 0, 0);
}

static __device__ __forceinline__ unsigned short f2bf_bits(float f) {
  union { __hip_bfloat16 b; unsigned short u; } cv;
  cv.b = __float2bfloat16(f);
  return cv.u;
}
static __device__ __forceinline__ float bf2f(short u) {
  union { float f; unsigned v; } cv;
  cv.v = ((unsigned)(unsigned short)u) << 16;
  return cv.f;
}

#define BAR() __builtin_amdgcn_s_barrier()
#define SBZ() __builtin_amdgcn_sched_barrier(0)
#define LGKM(n) asm volatile("s_waitcnt lgkmcnt(" #n ")" ::: "memory")
#define VMW(n) asm volatile("s_waitcnt vmcnt(" #n ")" ::: "memory")

// ---------------- merged fp32 -> bf16 convert (x | Wqk | Wvc) ----------------
__global__ __launch_bounds__(256) void cvt_all(const float* __restrict__ x,
                                               const float* __restrict__ wqk,
                                               const float* __restrict__ wvc,
                                               __hip_bfloat16* __restrict__ xb,
                                               __hip_bfloat16* __restrict__ wqkb,
                                               __hip_bfloat16* __restrict__ wvcb) {
  const int b = blockIdx.x;
  const float* in;
  __hip_bfloat16* out;
  long base;
  if (b < 8192)       { in = x;   out = xb;   base = (long)b * 1024; }
  else if (b < 9216)  { in = wqk; out = wqkb; base = (long)(b - 8192) * 1024; }
  else                { in = wvc; out = wvcb; base = (long)(b - 9216) * 1024; }
  const long i = base + threadIdx.x * 4;
  const float4 v = *(const float4*)(in + i);
  s16x4 o;
  o[0] = (short)f2bf_bits(v.x);
  o[1] = (short)f2bf_bits(v.y);
  o[2] = (short)f2bf_bits(v.z);
  o[3] = (short)f2bf_bits(v.w);
  *(s16x4*)(out + i) = o;
}

struct GemmDesc {
  const __hip_bfloat16* A; const __hip_bfloat16* B; void* C;
  int lda, ldb, ldc, nT, tpb; long sA, sB, sC; float cscale;
};

// ======= 8-phase 256x256 NT GEMM — m201-template-exact train (R13) =======
// C[m,n] = sum_k A[m,k]*B[n,k].  BK=64, 512 thr = 8 waves (2M x 4N), per-wave
// 128x64, acc[8][4].  LDS 128 KiB = 2 bufs x {A0,A1,B0,B1} x 16 KiB.
// KEY RELAYOUT vs R6/R7: region A_h = lo/hi 64-row halves of BOTH wm strips:
//   A_h holds global rows {wm*128 + h*64 + 0..63} at offset wm*8192.
// Retirement (reads complete at that phase's lgkm0, before its closing BAR):
//   buf0: A0 @P1, B0/B1 @P2, A1 @P3  (mirrored P5/P6/P7 for buf1)
// -> enables the template's even 1-half-tile/phase train w/ 3 in flight:
//   P1:A1(tb)  P2:A0(ta2) P3:B0(ta2) P4:B1(ta2) [VMW(6)]
//   P5:A1(ta2) P6:A0(tb2) P7:B0(tb2) P8:B1(tb2) [VMW(6)]
// Load-count audit (2 loads/half-tile): after P8' VMW(6): 6 outstanding
// (tb: A0,B0,B1 from P6',P7',P8').  @P4: 14 -> VMW(6) completes 8 oldest =
// all of tb (incl P1's A1, needed P7) => buf1 safe for P5-P8.  @P8: 14 ->
// completes all of ta2 => buf0 safe for next iter.  Stage-overwrite safety:
// every stage target's last read is >=1 closing-BAR earlier (two-barrier
// phase: lgkm0 BEFORE BAR2 certifies all waves' reads retired).
// Last iter: only P1 stages; VMW(2)@P4 (completes tb's A0,B0,B1; A1 needed
// P7), VMW(0)@P6 (drains A1 before P7's reads).
// Phase skeleton (template-exact): {reads|stage} -> [lgkm(8) if 12 reads] ->
// BAR -> lgkm(0) -> setprio(1) MFMAx16 setprio(0) -> [vmcnt] -> BAR.
// SBZ only after the 3 K-tile-boundary barriers (prologue, P4, P8) to pin
// next-tile ds_reads below the cross-wave landing guarantee.
template<int MODE>   // 0: fp32 store, 1: bf16 store (x cscale)
__global__ __launch_bounds__(512, 2) void gemm8t(GemmDesc g0, GemmDesc g1, int nb0, int K) {
  __shared__ char lds[131072];
  const int bid = blockIdx.x, nwg = gridDim.x;
  const int wg = (bid & 7) * (nwg >> 3) + (bid >> 3);   // XCD swizzle (nwg%8==0)
  GemmDesc g = (wg < nb0) ? g0 : g1;
  const int id = (wg < nb0) ? wg : wg - nb0;
  const int bz = id / g.tpb, tl = id - bz * g.tpb;
  const int bm = tl / g.nT, bn = tl - bm * g.nT;
  const long m0 = (long)bm * 256, n0 = (long)bn * 256;
  const __hip_bfloat16* Ab = g.A + bz * g.sA;
  const __hip_bfloat16* Bb = g.B + bz * g.sB;

  const int t = threadIdx.x, lane = t & 63, w = t >> 6;
  const int wm = w >> 2, wn = w & 3;
  const int lr = lane & 15, cs = lane >> 4;

  // stage sources: thread t covers chunk row srow (0..63), dest slot t&7;
  // source slot = (t&7) ^ (srow&7) (involution; chunk offset keeps row&7).
  const int srow = t >> 3;
  const int sslot = (t & 7) ^ (srow & 7);
  // A region h chunk i: global rows i*128 + h*64 + srow  (RELAYOUT)
  const __hip_bfloat16* aP[2][2];
  // B region h chunk i: global n-rows h*128 + i*64 + srow (unchanged)
  const __hip_bfloat16* bP[2][2];
  #pragma unroll
  for (int h = 0; h < 2; ++h)
    #pragma unroll
    for (int i = 0; i < 2; ++i) {
      aP[h][i] = Ab + (m0 + i * 128 + h * 64 + srow) * g.lda + sslot * 8;
      bP[h][i] = Bb + (n0 + h * 128 + i * 64 + srow) * g.ldb + sslot * 8;
    }

  // read-side swizzled LDS byte offsets.
  // af[mb*4+mm]: global row wm*128 + mb*64 + mm*16 + lr  ->  region mb,
  // chunk wm, within-chunk row mm*16+lr  (identical global mapping to R6).
  int aOf[8], bOf[4];
  #pragma unroll
  for (int mm = 0; mm < 8; ++mm)
    aOf[mm] = (mm >> 2) * 16384 + wm * 8192 + ((mm & 3) * 16 + lr) * 128 +
              ((cs ^ (lr & 7)) << 4);
  #pragma unroll
  for (int nf = 0; nf < 4; ++nf)
    bOf[nf] = 32768 + (wn >> 1) * 16384 + ((wn & 1) * 64 + nf * 16 + lr) * 128 +
              ((cs ^ (lr & 7)) << 4);

  f32x4 acc[8][4] = {};
  bf16x8 af[4][2], bqA[2][2], bqB[2][2];

  #define STG(P, h, kt, dbase) do { \
    async_cp16(P[h][0] + (long)(kt) * 64, lds + (dbase) + t * 16); \
    async_cp16(P[h][1] + (long)(kt) * 64, lds + (dbase) + 8192 + t * 16); } while (0)
  #define RD_AF(mb, bufb) do { _Pragma("unroll") for (int mm_ = 0; mm_ < 4; ++mm_) { \
      af[mm_][0] = *(const bf16x8*)(lds + (bufb) + aOf[(mb) * 4 + mm_]); \
      af[mm_][1] = *(const bf16x8*)(lds + (bufb) + (aOf[(mb) * 4 + mm_] ^ 64)); } } while (0)
  #define RD_BQ(dst, nb, bufb) do { _Pragma("unroll") for (int nf_ = 0; nf_ < 2; ++nf_) { \
      dst[nf_][0] = *(const bf16x8*)(lds + (bufb) + bOf[(nb) * 2 + nf_]); \
      dst[nf_][1] = *(const bf16x8*)(lds + (bufb) + (bOf[(nb) * 2 + nf_] ^ 64)); } } while (0)
  #define MM16(BQ, NB, MB) do { \
    __builtin_amdgcn_s_setprio(1); \
    _Pragma("unroll") for (int ks_ = 0; ks_ < 2; ++ks_) \
      _Pragma("unroll") for (int mm_ = 0; mm_ < 4; ++mm_) \
        _Pragma("unroll") for (int nf_ = 0; nf_ < 2; ++nf_) \
          acc[(MB) + mm_][(NB) + nf_] = __builtin_amdgcn_mfma_f32_16x16x32_bf16( \
              af[mm_][ks_], BQ[nf_][ks_], acc[(MB) + mm_][(NB) + nf_], 0, 0, 0); \
    __builtin_amdgcn_s_setprio(0); } while (0)

  const int nt = K >> 6, nJ = nt >> 1;
  // prologue: t0 {A0,B0,B1,A1} + t1 {A0,B0,B1} (7 half-tiles); VMW(6) drains
  // t0's 8 loads, leaves t1's 6 in flight (steady-state invariant).
  STG(aP, 0, 0, 0);     STG(bP, 0, 0, 32768);
  STG(bP, 1, 0, 49152); STG(aP, 1, 0, 16384);
  STG(aP, 0, 1, 65536); STG(bP, 0, 1, 65536 + 32768); STG(bP, 1, 1, 65536 + 49152);
  VMW(6);
  BAR(); SBZ();

  for (int j = 0; j < nJ; ++j) {
    const bool full = (j + 1 < nJ);
    const int tb = 2 * j + 1, ta2 = 2 * j + 2, tb2 = 2 * j + 3;
    // P1: Q(mlo,nlo) buf0; stage A1(tb)
    RD_AF(0, 0); RD_BQ(bqA, 0, 0);
    STG(aP, 1, tb, 65536 + 16384);
    LGKM(8);
    BAR(); LGKM(0);
    MM16(bqA, 0, 0);
    BAR();
    // P2: Q(mlo,nhi); stage A0(ta2)  [buf0.A0 retired @P1]
    RD_BQ(bqB, 1, 0);
    if (full) STG(aP, 0, ta2, 0);
    BAR(); LGKM(0);
    MM16(bqB, 2, 0);
    BAR();
    // P3: Q(mhi,nhi); stage B0(ta2)  [buf0.B retired @P2]
    RD_AF(1, 0);
    if (full) STG(bP, 0, ta2, 32768);
    BAR(); LGKM(0);
    MM16(bqB, 2, 4);
    BAR();
    // P4: Q(mhi,nlo); stage B1(ta2); K-tile wait
    if (full) STG(bP, 1, ta2, 49152);
    BAR();
    MM16(bqA, 0, 4);
    if (full) { VMW(6); } else { VMW(2); }
    BAR(); SBZ();
    // P5: Q(mlo,nlo) buf1; stage A1(ta2)  [buf0.A1 retired @P3]
    RD_AF(0, 65536); RD_BQ(bqA, 0, 65536);
    if (full) STG(aP, 1, ta2, 16384);
    LGKM(8);
    BAR(); LGKM(0);
    MM16(bqA, 0, 0);
    BAR();
    // P6: stage A0(tb2)  [buf1.A0 retired @P5]
    RD_BQ(bqB, 1, 65536);
    if (full) STG(aP, 0, tb2, 65536);
    BAR(); LGKM(0);
    MM16(bqB, 2, 0);
    if (!full) VMW(0);   // drain A1(tb) before P7's reads (last iter only)
    BAR();
    // P7: stage B0(tb2)  [buf1.B retired @P6]
    RD_AF(1, 65536);
    if (full) STG(bP, 0, tb2, 65536 + 32768);
    BAR(); LGKM(0);
    MM16(bqB, 2, 4);
    BAR();
    // P8: stage B1(tb2); K-tile wait
    if (full) STG(bP, 1, tb2, 65536 + 49152);
    BAR();
    MM16(bqA, 0, 4);
    if (full) { VMW(6); }
    BAR(); SBZ();
  }
  #undef STG
  #undef RD_AF
  #undef RD_BQ
  #undef MM16

  // epilogue: C/D mapping col=lane&15, row=(lane>>4)*4+reg  [verified m89/m91]
  const long crow0 = m0 + wm * 128 + cs * 4;
  const long ccol0 = n0 + wn * 64 + lr;
  if (MODE == 0) {
    float* C = (float*)g.C + bz * g.sC;
    #pragma unroll
    for (int mm = 0; mm < 8; ++mm)
      #pragma unroll
      for (int nf = 0; nf < 4; ++nf)
        #pragma unroll
        for (int rr = 0; rr < 4; ++rr)
          C[(crow0 + mm * 16 + rr) * g.ldc + ccol0 + nf * 16] = acc[mm][nf][rr];
  } else {
    __hip_bfloat16* C = (__hip_bfloat16*)g.C + bz * g.sC;
    #pragma unroll
    for (int mm = 0; mm < 8; ++mm)
      #pragma unroll
      for (int nf = 0; nf < 4; ++nf)
        #pragma unroll
        for (int rr = 0; rr < 4; ++rr)
          C[(crow0 + mm * 16 + rr) * g.ldc + ccol0 + nf * 16] =
              __float2bfloat16(acc[mm][nf][rr] * g.cscale);
  }
}

// ================= 16-wave tri-buffered NT GEMM (R11, proven for out) =================
template<int MODE, int BM_, int BK_>
__global__ __launch_bounds__(1024, 4) void gemm16(GemmDesc g0, GemmDesc g1, int nb0, int K) {
  constexpr int MR = BM_ / 64;
  constexpr int KR = BK_ / 32;
  constexpr int W  = BK_ * 2;
  constexpr int NB = (256 * W) / 16384;
  constexpr int BUFSZ = 16384 + NB * 16384;
  constexpr int KW = 1 + NB;
  __shared__ char lds[3 * BUFSZ];

  const int bid = blockIdx.x, nwg = gridDim.x;
  const int wg = (bid & 7) * (nwg >> 3) + (bid >> 3);
  GemmDesc g = (wg < nb0) ? g0 : g1;
  const int id = (wg < nb0) ? wg : wg - nb0;
  const int bz = id / g.tpb, tl = id - bz * g.tpb;
  const int bm = tl / g.nT, bn = tl - bm * g.nT;
  const long m0 = (long)bm * BM_, n0 = (long)bn * 256;
  const __hip_bfloat16* Ab = g.A + bz * g.sA;
  const __hip_bfloat16* Bb = g.B + bz * g.sB;

  const int t = threadIdx.x;
  const int lane = t & 63, w = t >> 6;
  const int wm = w >> 2, wn = w & 3;
  const int lr = lane & 15, cs = lane >> 4;

  const int rA  = t / (W / 16);
  const int dsl = t % (W / 16);
  const int ssl = dsl ^ ((W == 64) ? ((rA >> 1) & 3) : (rA & 7));
  const __hip_bfloat16* aSt  = Ab + (m0 + rA) * g.lda + ssl * 8;
  const __hip_bfloat16* bSt0 = Bb + (n0 + rA) * g.ldb + ssl * 8;
  const __hip_bfloat16* bSt1 = Bb + (n0 + 128 + rA) * g.ldb + ssl * 8;

  const int axor = (W == 64) ? (((lr >> 1) & 3) << 4) : ((lr & 7) << 4);
  int aRd[MR][KR], bRd[4][KR];
  #pragma unroll
  for (int mm = 0; mm < MR; ++mm)
    #pragma unroll
    for (int ks = 0; ks < KR; ++ks)
      aRd[mm][ks] = (wm * (BM_ / 4) + mm * 16 + lr) * W + ((((ks * 4 + cs) << 4) ^ axor));
  #pragma unroll
  for (int nf = 0; nf < 4; ++nf)
    #pragma unroll
    for (int ks = 0; ks < KR; ++ks)
      bRd[nf][ks] = 16384 + (wn * 64 + nf * 16 + lr) * W + ((((ks * 4 + cs) << 4) ^ axor));

  f32x4 acc[MR][4] = {};

  #define STAGE(kt, base) do { \
    async_cp16(aSt + (long)(kt) * BK_, lds + (base) + t * 16); \
    async_cp16(bSt0 + (long)(kt) * BK_, lds + (base) + 16384 + t * 16); \
    if (NB == 2) async_cp16(bSt1 + (long)(kt) * BK_, lds + (base) + 32768 + t * 16); \
  } while (0)
  #define VM_KW() do { if constexpr (KW == 2) { VMW(2); } else { VMW(3); } SBZ(); } while (0)

  const int nt = K / BK_;
  STAGE(0, 0);
  STAGE(1, BUFSZ);
  VM_KW();
  BAR();

  int rb = 0, sb = 2 * BUFSZ;
  for (int tt = 0; tt < nt; ++tt) {
    bf16x8 af[MR][KR], bq[4][KR];
    #pragma unroll
    for (int mm = 0; mm < MR; ++mm)
      #pragma unroll
      for (int ks = 0; ks < KR; ++ks)
        af[mm][ks] = *(const bf16x8*)(lds + rb + aRd[mm][ks]);
    #pragma unroll
    for (int nf = 0; nf < 4; ++nf)
      #pragma unroll
      for (int ks = 0; ks < KR; ++ks)
        bq[nf][ks] = *(const bf16x8*)(lds + rb + bRd[nf][ks]);
    if (tt + 2 < nt) STAGE(tt + 2, sb);
    #pragma unroll
    for (int ks = 0; ks < KR; ++ks)
      #pragma unroll
      for (int mm = 0; mm < MR; ++mm)
        #pragma unroll
        for (int nf = 0; nf < 4; ++nf)
          acc[mm][nf] = __builtin_amdgcn_mfma_f32_16x16x32_bf16(af[mm][ks], bq[nf][ks], acc[mm][nf], 0, 0, 0);
    if (tt + 2 < nt) { VM_KW(); } else { VMW(0); SBZ(); }
    BAR();
    rb = (rb == 2 * BUFSZ) ? 0 : rb + BUFSZ;
    sb = (sb == 2 * BUFSZ) ? 0 : sb + BUFSZ;
  }
  #undef STAGE
  #undef VM_KW

  const long crow0 = m0 + wm * (BM_ / 4) + cs * 4;
  const long ccol0 = n0 + wn * 64 + lr;
  if (MODE == 0) {
    float* C = (float*)g.C + bz * g.sC;
    #pragma unroll
    for (int mm = 0; mm < MR; ++mm)
      #pragma unroll
      for (int nf = 0; nf < 4; ++nf)
        #pragma unroll
        for (int rr = 0; rr < 4; ++rr)
          C[(crow0 + mm * 16 + rr) * g.ldc + ccol0 + nf * 16] = acc[mm][nf][rr];
  } else {
    __hip_bfloat16* C = (__hip_bfloat16*)g.C + bz * g.sC;
    #pragma unroll
    for (int mm = 0; mm < MR; ++mm)
      #pragma unroll
      for (int nf = 0; nf < 4; ++nf)
        #pragma unroll
        for (int rr = 0; rr < 4; ++rr)
          C[(crow0 + mm * 16 + rr) * g.ldc + ccol0 + nf * 16] =
              __float2bfloat16(acc[mm][nf][rr] * g.cscale);
  }
}

// ---------------- row softmax: bf16 scores (pre-scaled) + mask -> bf16 P in place ----
// No max-subtraction pass (R10-proven): unmasked |S| <= ~8 here, exp(S) <= e^8,
// row sums < 1e7 — exact ratios in f32.  Masked entries contribute 0.  Guard
// reproduces the reference's uniform 1/2048 for an all-masked row.
__global__ __launch_bounds__(256) void softmax_rows(__hip_bfloat16* __restrict__ S,
                                                    const int* __restrict__ Mask) {
  const long row = blockIdx.x;
  short* srow = (short*)(S + row * 2048);
  const int* mrow = Mask + row * 2048;
  const int t = threadIdx.x;
  const s16x8 sv = *(const s16x8*)(srow + t * 8);
  const int4 q0 = *(const int4*)(mrow + t * 8);
  const int4 q1 = *(const int4*)(mrow + t * 8 + 4);
  const int mk[8] = {q0.x, q0.y, q0.z, q0.w, q1.x, q1.y, q1.z, q1.w};

  float e[8];
  float s = 0.f;
  #pragma unroll
  for (int i = 0; i < 8; ++i) {
    e[i] = mk[i] ? __expf(bf2f(sv[i])) : 0.f;
    s += e[i];
  }
  #pragma unroll
  for (int off = 32; off > 0; off >>= 1) s += __shfl_xor(s, off);
  __shared__ float reds[4];
  if ((t & 63) == 0) reds[t >> 6] = s;
  __syncthreads();   // also orders all srow reads before the in-place write below
  s = reds[0] + reds[1] + reds[2] + reds[3];

  s16x8 o;
  if (s > 0.f) {
    const float inv = 1.f / s;
    #pragma unroll
    for (int i = 0; i < 8; ++i) o[i] = (short)f2bf_bits(e[i] * inv);
  } else {
    const unsigned short u = f2bf_bits(1.f / 2048.f);
    #pragma unroll
    for (int i = 0; i < 8; ++i) o[i] = (short)u;
  }
  *(s16x8*)(srow + t * 8) = o;
}

extern "C" void kernel_launch(void* const* d_in, const int* in_sizes, int n_in,
                              void* d_out, int out_size, void* d_ws, size_t ws_size,
                              hipStream_t stream) {
  const float* x   = (const float*)d_in[0];
  const int*   msk = (const int*)d_in[1];
  const float* Wqk = (const float*)d_in[2];
  const float* Wvc = (const float*)d_in[3];
  float* out = (float*)d_out;
  char* ws = (char*)d_ws;

  // workspace: x_bf16 | q_bf16 (pre-scaled by 1/32) | vT_bf16 | Wqk_bf16 | Wvc_bf16 | S_bf16
  __hip_bfloat16* xb   = (__hip_bfloat16*)(ws + 0);          // 16 MiB
  __hip_bfloat16* qb   = (__hip_bfloat16*)(ws + 16777216);   // 16 MiB
  __hip_bfloat16* vT   = (__hip_bfloat16*)(ws + 33554432);   // 16 MiB
  __hip_bfloat16* wqkb = (__hip_bfloat16*)(ws + 50331648);   // 2 MiB
  __hip_bfloat16* wvcb = (__hip_bfloat16*)(ws + 52428800);   // 2 MiB
  __hip_bfloat16* Sbf  = (__hip_bfloat16*)(ws + 54525952);   // 32 MiB

  cvt_all<<<dim3(10240), 256, 0, stream>>>(x, Wqk, Wvc, xb, wqkb, wvcb);

  // grouped: q = (x @ Wqk^T)/32  [8192x1024, 128 tiles]  +  vT[b] = Wvc @ x[b]^T [128 tiles]
  GemmDesc gq{xb,   wqkb, qb, 1024, 1024, 1024, 4, 128, 0L, 0L, 0L, 0.03125f};
  GemmDesc gv{wvcb, xb,   vT, 1024, 1024, 2048, 8, 32, 0L, 2097152L, 2097152L, 1.f};
  gemm8t<1><<<dim3(256), 512, 0, stream>>>(gq, gv, 128, 1024);

  // S[b] = q'[b] @ x[b]^T  (bf16 scores, already scaled)
  GemmDesc gs{qb, xb, Sbf, 1024, 1024, 2048, 8, 64, 2097152L, 2097152L, 4194304L, 1.f};
  gemm8t<1><<<dim3(256), 512, 0, stream>>>(gs, gs, 256, 1024);

  // softmax rows: bf16+mask -> bf16 P in place (stride 2048)
  softmax_rows<<<dim3(8192), 256, 0, stream>>>(Sbf, msk);

  // out[b] = P[b] @ vT[b]^T  (K=2048, fp32 out): 16-wave BK=64 variant, grid 256
  GemmDesc go{Sbf, vT, out, 2048, 2048, 1024, 4, 64, 4194304L, 2097152L, 2097152L, 1.f};
  gemm16<0, 128, 64><<<dim3(256), 1024, 0, stream>>>(go, go, 256, 2048);
}

// Round 14
// 138.790 us; speedup vs baseline: 1.0243x; 1.0243x over previous
//
#include <hip/hip_runtime.h>
#include <hip/hip_bf16.h>

typedef short bf16x8 __attribute__((ext_vector_type(8)));
typedef short s16x4  __attribute__((ext_vector_type(4)));
typedef short s16x8  __attribute__((ext_vector_type(8)));
typedef float f32x4  __attribute__((ext_vector_type(4)));

static __device__ __forceinline__ void async_cp16(const void* g, void* l) {
  __builtin_amdgcn_global_load_lds(
      (const __attribute__((address_space(1))) unsigned int*)g,
      (__attribute__((address_space(3))) unsigned int*)l, 16, 0, 0);
}

static __device__ __forceinline__ unsigned short f2bf_bits(float f) {
  union { __hip_bfloat16 b; unsigned short u; } cv;
  cv.b = __float2bfloat16(f);
  return cv.u;
}
static __device__ __forceinline__ float bf2f(short u) {
  union { float f; unsigned v; } cv;
  cv.v = ((unsigned)(unsigned short)u) << 16;
  return cv.f;
}

#define BAR() __builtin_amdgcn_s_barrier()
#define SBZ() __builtin_amdgcn_sched_barrier(0)
#define LGKM0() do { asm volatile("s_waitcnt lgkmcnt(0)" ::: "memory"); SBZ(); } while (0)
#define VMW(n) do { asm volatile("s_waitcnt vmcnt(" #n ")" ::: "memory"); SBZ(); } while (0)

// ---------------- merged fp32 -> bf16 convert (x | Wqk | Wvc) ----------------
__global__ __launch_bounds__(256) void cvt_all(const float* __restrict__ x,
                                               const float* __restrict__ wqk,
                                               const float* __restrict__ wvc,
                                               __hip_bfloat16* __restrict__ xb,
                                               __hip_bfloat16* __restrict__ wqkb,
                                               __hip_bfloat16* __restrict__ wvcb) {
  const int b = blockIdx.x;
  const float* in;
  __hip_bfloat16* out;
  long base;
  if (b < 8192)       { in = x;   out = xb;   base = (long)b * 1024; }
  else if (b < 9216)  { in = wqk; out = wqkb; base = (long)(b - 8192) * 1024; }
  else                { in = wvc; out = wvcb; base = (long)(b - 9216) * 1024; }
  const long i = base + threadIdx.x * 4;
  const float4 v = *(const float4*)(in + i);
  s16x4 o;
  o[0] = (short)f2bf_bits(v.x);
  o[1] = (short)f2bf_bits(v.y);
  o[2] = (short)f2bf_bits(v.z);
  o[3] = (short)f2bf_bits(v.w);
  *(s16x4*)(out + i) = o;
}

struct GemmDesc {
  const __hip_bfloat16* A; const __hip_bfloat16* B; void* C;
  int lda, ldb, ldc, nT, tpb; long sA, sB, sC; float cscale;
};

// ================= 8-phase 256x256 NT GEMM (R6/R10/R11, best passing for qv/S) ======
// C[m,n] = sum_k A[m,k]*B[n,k].  BK=64, 512 thr = 8 waves (2M x 4N), per-wave
// 128x64, acc[8][4].  LDS 128 KiB = 2 bufs x 4 regions x 16 KiB (A0,A1,B0,B1);
// region = [128 rows][128 B], 16B slot s of row r stored at s^(r&7)
// (involution, staged via inverse-permuted GLOBAL source slot; 0 conflicts
// measured R3-R13).  Per-phase: {reads | stage} -> lgkm0 -> MFMA16 -> [vm] ->
// BAR; stages P1:A0(tb) P2:A1(tb) P3:B0(ta+2) P4:B1(ta+2) P5:A0(ta+2)
// P6:A1(ta+2) P7:B0(tb+2) P8:B1(tb+2); vmcnt(4) at P4/P8; every stage targets
// a region whose reads completed at an earlier phase's lgkm0.
// NOTE (R4-R13 ledger): 12 structural variants of this loop (barrier count,
// wave count, BK, buffer depth, stage-train spread, relayout, reg pipelining)
// all measure 39-42 us at these shapes — this is the plateau config.
template<int MODE>   // 0: fp32 store, 1: bf16 store (x cscale)
__global__ __launch_bounds__(512, 2) void gemm8p(GemmDesc g0, GemmDesc g1, int nb0, int K) {
  __shared__ char lds[131072];
  const int bid = blockIdx.x, nwg = gridDim.x;
  const int wg = (bid & 7) * (nwg >> 3) + (bid >> 3);   // XCD swizzle (nwg%8==0)
  GemmDesc g = (wg < nb0) ? g0 : g1;
  const int id = (wg < nb0) ? wg : wg - nb0;
  const int bz = id / g.tpb, tl = id - bz * g.tpb;
  const int bm = tl / g.nT, bn = tl - bm * g.nT;
  const long m0 = (long)bm * 256, n0 = (long)bn * 256;
  const __hip_bfloat16* Ab = g.A + bz * g.sA;
  const __hip_bfloat16* Bb = g.B + bz * g.sB;

  const int t = threadIdx.x, lane = t & 63, w = t >> 6;
  const int wm = w >> 2, wn = w & 3;
  const int lr = lane & 15, cs = lane >> 4;

  const int srow = t >> 3;
  const int sslot = (t & 7) ^ (srow & 7);
  const __hip_bfloat16* aP[2][2];
  const __hip_bfloat16* bP[2][2];
  #pragma unroll
  for (int h = 0; h < 2; ++h)
    #pragma unroll
    for (int i = 0; i < 2; ++i) {
      aP[h][i] = Ab + (m0 + h * 128 + i * 64 + srow) * g.lda + sslot * 8;
      bP[h][i] = Bb + (n0 + h * 128 + i * 64 + srow) * g.ldb + sslot * 8;
    }

  int aOf[8], bOf[4];
  #pragma unroll
  for (int mm = 0; mm < 8; ++mm)
    aOf[mm] = wm * 16384 + (mm * 16 + lr) * 128 + ((cs ^ (lr & 7)) << 4);
  #pragma unroll
  for (int nf = 0; nf < 4; ++nf)
    bOf[nf] = 32768 + (wn >> 1) * 16384 + ((wn & 1) * 64 + nf * 16 + lr) * 128 +
              ((cs ^ (lr & 7)) << 4);

  f32x4 acc[8][4] = {};
  bf16x8 af[4][2], bqA[2][2], bqB[2][2];

  #define STG(P, h, kt, dbase) do { \
    async_cp16(P[h][0] + (long)(kt) * 64, lds + (dbase) + t * 16); \
    async_cp16(P[h][1] + (long)(kt) * 64, lds + (dbase) + 8192 + t * 16); } while (0)
  #define RD_AF(mb, bufb) do { _Pragma("unroll") for (int mm_ = 0; mm_ < 4; ++mm_) { \
      af[mm_][0] = *(const bf16x8*)(lds + (bufb) + aOf[(mb) * 4 + mm_]); \
      af[mm_][1] = *(const bf16x8*)(lds + (bufb) + (aOf[(mb) * 4 + mm_] ^ 64)); } } while (0)
  #define RD_BQ(dst, nb, bufb) do { _Pragma("unroll") for (int nf_ = 0; nf_ < 2; ++nf_) { \
      dst[nf_][0] = *(const bf16x8*)(lds + (bufb) + bOf[(nb) * 2 + nf_]); \
      dst[nf_][1] = *(const bf16x8*)(lds + (bufb) + (bOf[(nb) * 2 + nf_] ^ 64)); } } while (0)
  #define MM16(BQ, NB, MB) do { \
    __builtin_amdgcn_s_setprio(1); \
    _Pragma("unroll") for (int ks_ = 0; ks_ < 2; ++ks_) \
      _Pragma("unroll") for (int mm_ = 0; mm_ < 4; ++mm_) \
        _Pragma("unroll") for (int nf_ = 0; nf_ < 2; ++nf_) \
          acc[(MB) + mm_][(NB) + nf_] = __builtin_amdgcn_mfma_f32_16x16x32_bf16( \
              af[mm_][ks_], BQ[nf_][ks_], acc[(MB) + mm_][(NB) + nf_], 0, 0, 0); \
    __builtin_amdgcn_s_setprio(0); } while (0)

  const int nt = K >> 6, nJ = nt >> 1;
  STG(bP, 0, 0, 32768); STG(bP, 1, 0, 49152);
  STG(aP, 0, 0, 0);     STG(aP, 1, 0, 16384);
  STG(bP, 0, 1, 65536 + 32768); STG(bP, 1, 1, 65536 + 49152);
  VMW(4);
  BAR(); SBZ();

  for (int j = 0; j < nJ; ++j) {
    const bool full = (j + 1 < nJ);
    const int tb = 2 * j + 1, ta2 = 2 * j + 2, tb2 = 2 * j + 3;
    // P1
    RD_AF(0, 0); RD_BQ(bqA, 0, 0);
    STG(aP, 0, tb, 65536);
    LGKM0();
    MM16(bqA, 0, 0);
    BAR(); SBZ();
    // P2
    RD_BQ(bqB, 1, 0);
    STG(aP, 1, tb, 65536 + 16384);
    LGKM0();
    MM16(bqB, 2, 0);
    BAR(); SBZ();
    // P3
    RD_AF(1, 0);
    if (full) STG(bP, 0, ta2, 32768);
    LGKM0();
    MM16(bqB, 2, 4);
    BAR(); SBZ();
    // P4
    if (full) STG(bP, 1, ta2, 49152);
    MM16(bqA, 0, 4);
    if (full) { VMW(4); } else { VMW(0); }
    BAR(); SBZ();
    // P5
    RD_AF(0, 65536); RD_BQ(bqA, 0, 65536);
    if (full) STG(aP, 0, ta2, 0);
    LGKM0();
    MM16(bqA, 0, 0);
    BAR(); SBZ();
    // P6
    RD_BQ(bqB, 1, 65536);
    if (full) STG(aP, 1, ta2, 16384);
    LGKM0();
    MM16(bqB, 2, 0);
    BAR(); SBZ();
    // P7
    RD_AF(1, 65536);
    if (full) STG(bP, 0, tb2, 65536 + 32768);
    LGKM0();
    MM16(bqB, 2, 4);
    BAR(); SBZ();
    // P8
    if (full) STG(bP, 1, tb2, 65536 + 49152);
    MM16(bqA, 0, 4);
    if (full) { VMW(4); } else { VMW(0); }
    BAR(); SBZ();
  }
  #undef STG
  #undef RD_AF
  #undef RD_BQ
  #undef MM16

  // epilogue: C/D mapping col=lane&15, row=(lane>>4)*4+reg  [verified m89/m91]
  const long crow0 = m0 + wm * 128 + cs * 4;
  const long ccol0 = n0 + wn * 64 + lr;
  if (MODE == 0) {
    float* C = (float*)g.C + bz * g.sC;
    #pragma unroll
    for (int mm = 0; mm < 8; ++mm)
      #pragma unroll
      for (int nf = 0; nf < 4; ++nf)
        #pragma unroll
        for (int rr = 0; rr < 4; ++rr)
          C[(crow0 + mm * 16 + rr) * g.ldc + ccol0 + nf * 16] = acc[mm][nf][rr];
  } else {
    __hip_bfloat16* C = (__hip_bfloat16*)g.C + bz * g.sC;
    #pragma unroll
    for (int mm = 0; mm < 8; ++mm)
      #pragma unroll
      for (int nf = 0; nf < 4; ++nf)
        #pragma unroll
        for (int rr = 0; rr < 4; ++rr)
          C[(crow0 + mm * 16 + rr) * g.ldc + ccol0 + nf * 16] =
              __float2bfloat16(acc[mm][nf][rr] * g.cscale);
  }
}

// ================= 16-wave tri-buffered NT GEMM (R11, proven for out) =================
template<int MODE, int BM_, int BK_>
__global__ __launch_bounds__(1024, 4) void gemm16(GemmDesc g0, GemmDesc g1, int nb0, int K) {
  constexpr int MR = BM_ / 64;
  constexpr int KR = BK_ / 32;
  constexpr int W  = BK_ * 2;
  constexpr int NB = (256 * W) / 16384;
  constexpr int BUFSZ = 16384 + NB * 16384;
  constexpr int KW = 1 + NB;
  __shared__ char lds[3 * BUFSZ];

  const int bid = blockIdx.x, nwg = gridDim.x;
  const int wg = (bid & 7) * (nwg >> 3) + (bid >> 3);
  GemmDesc g = (wg < nb0) ? g0 : g1;
  const int id = (wg < nb0) ? wg : wg - nb0;
  const int bz = id / g.tpb, tl = id - bz * g.tpb;
  const int bm = tl / g.nT, bn = tl - bm * g.nT;
  const long m0 = (long)bm * BM_, n0 = (long)bn * 256;
  const __hip_bfloat16* Ab = g.A + bz * g.sA;
  const __hip_bfloat16* Bb = g.B + bz * g.sB;

  const int t = threadIdx.x;
  const int lane = t & 63, w = t >> 6;
  const int wm = w >> 2, wn = w & 3;
  const int lr = lane & 15, cs = lane >> 4;

  const int rA  = t / (W / 16);
  const int dsl = t % (W / 16);
  const int ssl = dsl ^ ((W == 64) ? ((rA >> 1) & 3) : (rA & 7));
  const __hip_bfloat16* aSt  = Ab + (m0 + rA) * g.lda + ssl * 8;
  const __hip_bfloat16* bSt0 = Bb + (n0 + rA) * g.ldb + ssl * 8;
  const __hip_bfloat16* bSt1 = Bb + (n0 + 128 + rA) * g.ldb + ssl * 8;

  const int axor = (W == 64) ? (((lr >> 1) & 3) << 4) : ((lr & 7) << 4);
  int aRd[MR][KR], bRd[4][KR];
  #pragma unroll
  for (int mm = 0; mm < MR; ++mm)
    #pragma unroll
    for (int ks = 0; ks < KR; ++ks)
      aRd[mm][ks] = (wm * (BM_ / 4) + mm * 16 + lr) * W + ((((ks * 4 + cs) << 4) ^ axor));
  #pragma unroll
  for (int nf = 0; nf < 4; ++nf)
    #pragma unroll
    for (int ks = 0; ks < KR; ++ks)
      bRd[nf][ks] = 16384 + (wn * 64 + nf * 16 + lr) * W + ((((ks * 4 + cs) << 4) ^ axor));

  f32x4 acc[MR][4] = {};

  #define STAGE(kt, base) do { \
    async_cp16(aSt + (long)(kt) * BK_, lds + (base) + t * 16); \
    async_cp16(bSt0 + (long)(kt) * BK_, lds + (base) + 16384 + t * 16); \
    if (NB == 2) async_cp16(bSt1 + (long)(kt) * BK_, lds + (base) + 32768 + t * 16); \
  } while (0)
  #define VM_KW() do { if constexpr (KW == 2) { VMW(2); } else { VMW(3); } } while (0)

  const int nt = K / BK_;
  STAGE(0, 0);
  STAGE(1, BUFSZ);
  VM_KW();
  BAR();

  int rb = 0, sb = 2 * BUFSZ;
  for (int tt = 0; tt < nt; ++tt) {
    bf16x8 af[MR][KR], bq[4][KR];
    #pragma unroll
    for (int mm = 0; mm < MR; ++mm)
      #pragma unroll
      for (int ks = 0; ks < KR; ++ks)
        af[mm][ks] = *(const bf16x8*)(lds + rb + aRd[mm][ks]);
    #pragma unroll
    for (int nf = 0; nf < 4; ++nf)
      #pragma unroll
      for (int ks = 0; ks < KR; ++ks)
        bq[nf][ks] = *(const bf16x8*)(lds + rb + bRd[nf][ks]);
    if (tt + 2 < nt) STAGE(tt + 2, sb);
    // no manual lgkm drain: compiler interleaves MFMA with the ds_read tail
    #pragma unroll
    for (int ks = 0; ks < KR; ++ks)
      #pragma unroll
      for (int mm = 0; mm < MR; ++mm)
        #pragma unroll
        for (int nf = 0; nf < 4; ++nf)
          acc[mm][nf] = __builtin_amdgcn_mfma_f32_16x16x32_bf16(af[mm][ks], bq[nf][ks], acc[mm][nf], 0, 0, 0);
    if (tt + 2 < nt) { VM_KW(); } else { VMW(0); }
    BAR();
    rb = (rb == 2 * BUFSZ) ? 0 : rb + BUFSZ;
    sb = (sb == 2 * BUFSZ) ? 0 : sb + BUFSZ;
  }
  #undef STAGE
  #undef VM_KW

  const long crow0 = m0 + wm * (BM_ / 4) + cs * 4;
  const long ccol0 = n0 + wn * 64 + lr;
  if (MODE == 0) {
    float* C = (float*)g.C + bz * g.sC;
    #pragma unroll
    for (int mm = 0; mm < MR; ++mm)
      #pragma unroll
      for (int nf = 0; nf < 4; ++nf)
        #pragma unroll
        for (int rr = 0; rr < 4; ++rr)
          C[(crow0 + mm * 16 + rr) * g.ldc + ccol0 + nf * 16] = acc[mm][nf][rr];
  } else {
    __hip_bfloat16* C = (__hip_bfloat16*)g.C + bz * g.sC;
    #pragma unroll
    for (int mm = 0; mm < MR; ++mm)
      #pragma unroll
      for (int nf = 0; nf < 4; ++nf)
        #pragma unroll
        for (int rr = 0; rr < 4; ++rr)
          C[(crow0 + mm * 16 + rr) * g.ldc + ccol0 + nf * 16] =
              __float2bfloat16(acc[mm][nf][rr] * g.cscale);
  }
}

// ---------------- row softmax: bf16 scores (pre-scaled) + mask -> bf16 P in place ----
// No max-subtraction pass (R10-proven): unmasked |S| <= ~8 here, exp(S) <= e^8,
// row sums < 1e7 — exact ratios in f32.  Masked entries contribute 0.  Guard
// reproduces the reference's uniform 1/2048 for an all-masked row.
__global__ __launch_bounds__(256) void softmax_rows(__hip_bfloat16* __restrict__ S,
                                                    const int* __restrict__ Mask) {
  const long row = blockIdx.x;
  short* srow = (short*)(S + row * 2048);
  const int* mrow = Mask + row * 2048;
  const int t = threadIdx.x;
  const s16x8 sv = *(const s16x8*)(srow + t * 8);
  const int4 q0 = *(const int4*)(mrow + t * 8);
  const int4 q1 = *(const int4*)(mrow + t * 8 + 4);
  const int mk[8] = {q0.x, q0.y, q0.z, q0.w, q1.x, q1.y, q1.z, q1.w};

  float e[8];
  float s = 0.f;
  #pragma unroll
  for (int i = 0; i < 8; ++i) {
    e[i] = mk[i] ? __expf(bf2f(sv[i])) : 0.f;
    s += e[i];
  }
  #pragma unroll
  for (int off = 32; off > 0; off >>= 1) s += __shfl_xor(s, off);
  __shared__ float reds[4];
  if ((t & 63) == 0) reds[t >> 6] = s;
  __syncthreads();   // also orders all srow reads before the in-place write below
  s = reds[0] + reds[1] + reds[2] + reds[3];

  s16x8 o;
  if (s > 0.f) {
    const float inv = 1.f / s;
    #pragma unroll
    for (int i = 0; i < 8; ++i) o[i] = (short)f2bf_bits(e[i] * inv);
  } else {
    const unsigned short u = f2bf_bits(1.f / 2048.f);
    #pragma unroll
    for (int i = 0; i < 8; ++i) o[i] = (short)u;
  }
  *(s16x8*)(srow + t * 8) = o;
}

extern "C" void kernel_launch(void* const* d_in, const int* in_sizes, int n_in,
                              void* d_out, int out_size, void* d_ws, size_t ws_size,
                              hipStream_t stream) {
  const float* x   = (const float*)d_in[0];
  const int*   msk = (const int*)d_in[1];
  const float* Wqk = (const float*)d_in[2];
  const float* Wvc = (const float*)d_in[3];
  float* out = (float*)d_out;
  char* ws = (char*)d_ws;

  // workspace: x_bf16 | q_bf16 (pre-scaled by 1/32) | vT_bf16 | Wqk_bf16 | Wvc_bf16 | S_bf16
  __hip_bfloat16* xb   = (__hip_bfloat16*)(ws + 0);          // 16 MiB
  __hip_bfloat16* qb   = (__hip_bfloat16*)(ws + 16777216);   // 16 MiB
  __hip_bfloat16* vT   = (__hip_bfloat16*)(ws + 33554432);   // 16 MiB
  __hip_bfloat16* wqkb = (__hip_bfloat16*)(ws + 50331648);   // 2 MiB
  __hip_bfloat16* wvcb = (__hip_bfloat16*)(ws + 52428800);   // 2 MiB
  __hip_bfloat16* Sbf  = (__hip_bfloat16*)(ws + 54525952);   // 32 MiB

  cvt_all<<<dim3(10240), 256, 0, stream>>>(x, Wqk, Wvc, xb, wqkb, wvcb);

  // grouped: q = (x @ Wqk^T)/32  [8192x1024, 128 tiles]  +  vT[b] = Wvc @ x[b]^T [128 tiles]
  GemmDesc gq{xb,   wqkb, qb, 1024, 1024, 1024, 4, 128, 0L, 0L, 0L, 0.03125f};
  GemmDesc gv{wvcb, xb,   vT, 1024, 1024, 2048, 8, 32, 0L, 2097152L, 2097152L, 1.f};
  gemm8p<1><<<dim3(256), 512, 0, stream>>>(gq, gv, 128, 1024);

  // S[b] = q'[b] @ x[b]^T  (bf16 scores, already scaled)
  GemmDesc gs{qb, xb, Sbf, 1024, 1024, 2048, 8, 64, 2097152L, 2097152L, 4194304L, 1.f};
  gemm8p<1><<<dim3(256), 512, 0, stream>>>(gs, gs, 256, 1024);

  // softmax rows: bf16+mask -> bf16 P in place (stride 2048)
  softmax_rows<<<dim3(8192), 256, 0, stream>>>(Sbf, msk);

  // out[b] = P[b] @ vT[b]^T  (K=2048, fp32 out): 16-wave BK=64 variant, grid 256
  GemmDesc go{Sbf, vT, out, 2048, 2048, 1024, 4, 64, 4194304L, 2097152L, 2097152L, 1.f};
  gemm16<0, 128, 64><<<dim3(256), 1024, 0, stream>>>(go, go, 256, 2048);
}